// Round 6
// baseline (99.059 us; speedup 1.0000x reference)
//
#include <hip/hip_runtime.h>

// TensorProduct as dense bilinear form:
//   out[b,mo,c] = sum_{m1,m2} W[mo][m1][m2] * x1[b,m1,c] * x2[b,m2,c]
// W rows padded to stride 32: W[(mo*25+m1)*32 + m2], 80 KB in d_ws.
// (seg,M1,M2) triples unique (validated R3-R5) -> plain stores, no atomics.
//
// build_w: 25 one-wave blocks; block mo zeroes ITS padded slice then scatters
// ITS seg-segment (disjoint -> race-free). 2 graph nodes total (was 3).
// tp_dense: thread = (mo,b,c-pair), float2/thread; x columns in ~100 VGPRs,
// W rows wave-uniform (scalar loads -> SGPR operand on v_fmac).
// NEW: XCD swizzle — all 25 mo-blocks of one b land on XCD b&7, so x re-reads
// (82 MB/call total) hit that XCD's own L2 (16 b x 51 KB = 820 KB << 4 MB)
// instead of thrashing to Infinity Cache.

#define NUM_M 25
#define C_DIM 128
#define W_RSTRIDE 32
#define W_SLICE (NUM_M * W_RSTRIDE)          // 800 floats per mo-slice

__device__ __forceinline__ int wave_lower_bound(const int* __restrict__ seg,
                                                int nnz, int key) {
    const int lane = threadIdx.x & 63;
    int lo = 0, hi = nnz;
    while (hi > lo) {
        const int len = hi - lo;
        const int S = (len + 63) >> 6;
        const int idx = lo + lane * S;
        bool pred = false;
        if (idx < hi) pred = (seg[idx] < key);
        const unsigned long long bal = __ballot(pred);
        const int c = __popcll(bal);
        if (c == 0) { hi = lo; break; }
        int nhi = lo + c * S;
        if (nhi > hi) nhi = hi;
        lo = lo + (c - 1) * S + 1;
        hi = nhi;
    }
    return lo;
}

__global__ __launch_bounds__(64) void build_w(
    const float* __restrict__ cg, const int* __restrict__ M1,
    const int* __restrict__ M2, const int* __restrict__ seg,
    int nnz, float* __restrict__ W) {
    const int mo   = blockIdx.x;             // 0..24
    const int lane = threadIdx.x;
    float* Wmo = W + mo * W_SLICE;
    const int lo = wave_lower_bound(seg, nnz, mo);
    const int hi = wave_lower_bound(seg, nnz, mo + 1);
    for (int i = lane; i < W_SLICE; i += 64) Wmo[i] = 0.f;
    __syncthreads();                          // drain zero-stores before scatter
    for (int n = lo + lane; n < hi; n += 64)
        Wmo[M1[n] * W_RSTRIDE + M2[n]] = cg[n];   // unique -> plain store
}

__global__ __launch_bounds__(64, 2) void tp_dense(
    const float* __restrict__ x1, const float* __restrict__ x2,
    const float* __restrict__ W, float* __restrict__ out) {
    const int lane = threadIdx.x;            // 0..63 -> c-pair
    const int bid  = blockIdx.x;             // 0..3199 linear
    // XCD swizzle: xcd = bid&7; all blocks of batch b have b&7 == xcd.
    const int xcd  = bid & 7;
    const int slot = bid >> 3;               // 0..399
    const int mo   = slot >> 4;              // 0..24
    const int b    = ((slot & 15) << 3) | xcd;   // 0..127

    const float*  __restrict__ Wm  = W + mo * W_SLICE;           // uniform
    const float2* __restrict__ x1b = (const float2*)x1 + b * (NUM_M * 64) + lane;
    const float2* __restrict__ x2b = (const float2*)x2 + b * (NUM_M * 64) + lane;

    float2 x1v[NUM_M], x2v[NUM_M];
#pragma unroll
    for (int m = 0; m < NUM_M; ++m) x2v[m] = x2b[m * 64];        // L2-local
#pragma unroll
    for (int m = 0; m < NUM_M; ++m) x1v[m] = x1b[m * 64];

    float2 acc0 = {0.f, 0.f}, acc1 = {0.f, 0.f};
    float2 acc2 = {0.f, 0.f}, acc3 = {0.f, 0.f};

#pragma unroll
    for (int m1 = 0; m1 < NUM_M; ++m1) {
        const float* __restrict__ wr = Wm + m1 * W_RSTRIDE;      // 128B-aligned
        float2 t0, t1, t2, t3;
        t0.x = wr[24] * x2v[24].x; t0.y = wr[24] * x2v[24].y;
        t1 = {0.f, 0.f}; t2 = {0.f, 0.f}; t3 = {0.f, 0.f};
#pragma unroll
        for (int m2 = 0; m2 < 24; m2 += 4) {
            t0.x = fmaf(wr[m2 + 0], x2v[m2 + 0].x, t0.x);
            t0.y = fmaf(wr[m2 + 0], x2v[m2 + 0].y, t0.y);
            t1.x = fmaf(wr[m2 + 1], x2v[m2 + 1].x, t1.x);
            t1.y = fmaf(wr[m2 + 1], x2v[m2 + 1].y, t1.y);
            t2.x = fmaf(wr[m2 + 2], x2v[m2 + 2].x, t2.x);
            t2.y = fmaf(wr[m2 + 2], x2v[m2 + 2].y, t2.y);
            t3.x = fmaf(wr[m2 + 3], x2v[m2 + 3].x, t3.x);
            t3.y = fmaf(wr[m2 + 3], x2v[m2 + 3].y, t3.y);
        }
        float2 t;
        t.x = (t0.x + t1.x) + (t2.x + t3.x);
        t.y = (t0.y + t1.y) + (t2.y + t3.y);
        const float2 a = x1v[m1];
        switch (m1 & 3) {
            case 0:  acc0.x = fmaf(a.x, t.x, acc0.x); acc0.y = fmaf(a.y, t.y, acc0.y); break;
            case 1:  acc1.x = fmaf(a.x, t.x, acc1.x); acc1.y = fmaf(a.y, t.y, acc1.y); break;
            case 2:  acc2.x = fmaf(a.x, t.x, acc2.x); acc2.y = fmaf(a.y, t.y, acc2.y); break;
            default: acc3.x = fmaf(a.x, t.x, acc3.x); acc3.y = fmaf(a.y, t.y, acc3.y); break;
        }
    }

    float2 r;
    r.x = (acc0.x + acc1.x) + (acc2.x + acc3.x);
    r.y = (acc0.y + acc1.y) + (acc2.y + acc3.y);
    ((float2*)out)[(b * NUM_M + mo) * 64 + lane] = r;
}

extern "C" void kernel_launch(void* const* d_in, const int* in_sizes, int n_in,
                              void* d_out, int out_size, void* d_ws, size_t ws_size,
                              hipStream_t stream) {
    const float* x1  = (const float*)d_in[0];
    const float* x2  = (const float*)d_in[1];
    const float* cg  = (const float*)d_in[2];
    const int*   M1  = (const int*)d_in[3];
    const int*   M2  = (const int*)d_in[4];
    const int*   seg = (const int*)d_in[5];
    const int    nnz = in_sizes[2];
    float* W   = (float*)d_ws;               // 80 KB padded dense CG tensor
    float* out = (float*)d_out;

    build_w<<<NUM_M, 64, 0, stream>>>(cg, M1, M2, seg, nnz, W);
    tp_dense<<<NUM_M * 128, 64, 0, stream>>>(x1, x2, W, out);
}